// Round 3
// baseline (1500.197 us; speedup 1.0000x reference)
//
#include <hip/hip_runtime.h>
#include <hip/hip_bf16.h>
#include <stdint.h>

// Problem constants
#define B_    16
#define C_IN  64
#define C_OUT 32
#define V_HI  163842
#define V_LO  40962
#define K_    7
#define TOTAL_E (V_LO * K_)            // 286734 entries in inverse map
#define NPART 641                      // ceil(V_HI/256)
#define NTILE 161                      // ceil(V_HI/1024)

typedef float f4 __attribute__((ext_vector_type(4)));
typedef float f2 __attribute__((ext_vector_type(2)));

// ---------------------------------------------------------------------------
// Pass 1: h[b,o,v] = sum_c x[b,c,v]*W[o,c] + bias[o], stored as bf16.
// 4 v per thread; W read from LDS as float4 (1 ds_read_b128 per o per 4 c)
// -> LDS-issue count cut ~10x vs scalar version. x loads as float2 (rows are
// only 8B-aligned since V_LO*4 % 16 != 0).
// ---------------------------------------------------------------------------
__global__ __launch_bounds__(256) void compute_h_k(
    const float* __restrict__ x, const float* __restrict__ W,
    const float* __restrict__ bias, ushort* __restrict__ h)
{
    __shared__ float sW[C_OUT * C_IN];   // 8 KB
    __shared__ float sB[C_OUT];
    int t = threadIdx.x;
    for (int i = t; i < C_OUT * C_IN; i += 256) sW[i] = W[i];
    if (t < C_OUT) sB[t] = bias[t];
    __syncthreads();

    int b  = blockIdx.y;
    int v0 = (blockIdx.x * 256 + t) * 4;
    if (v0 >= V_LO) return;

    const float* xb = x + (size_t)b * C_IN * V_LO;

    float acc[C_OUT][4];
#pragma unroll
    for (int o = 0; o < C_OUT; ++o)
#pragma unroll
        for (int j = 0; j < 4; ++j) acc[o][j] = 0.0f;

    if (v0 + 4 <= V_LO) {
        for (int c0 = 0; c0 < C_IN; c0 += 4) {
            float xv[4][4];
#pragma unroll
            for (int cc = 0; cc < 4; ++cc) {
                const float* p = xb + (size_t)(c0 + cc) * V_LO + v0;
                f2 a = *(const f2*)p;          // 8B aligned
                f2 bq = *(const f2*)(p + 2);
                xv[cc][0] = a[0]; xv[cc][1] = a[1];
                xv[cc][2] = bq[0]; xv[cc][3] = bq[1];
            }
#pragma unroll
            for (int o = 0; o < C_OUT; ++o) {
                f4 w = *(const f4*)(&sW[o * C_IN + c0]);   // b128 broadcast
#pragma unroll
                for (int j = 0; j < 4; ++j)
                    acc[o][j] += w[0]*xv[0][j] + w[1]*xv[1][j]
                               + w[2]*xv[2][j] + w[3]*xv[3][j];
            }
        }
        ushort* hp = h + (size_t)b * C_OUT * V_LO + v0;
#pragma unroll
        for (int o = 0; o < C_OUT; ++o) {
            ushort us[4];
#pragma unroll
            for (int j = 0; j < 4; ++j) {
                __hip_bfloat16 bf = __float2bfloat16(acc[o][j] + sB[o]);
                us[j] = *(ushort*)&bf;
            }
            ushort2 p0; p0.x = us[0]; p0.y = us[1];
            ushort2 p1; p1.x = us[2]; p1.y = us[3];
            *(ushort2*)(hp + (size_t)o * V_LO)     = p0;   // 4B aligned
            *(ushort2*)(hp + (size_t)o * V_LO + 2) = p1;
        }
    } else {
        // tail (last 2 v's): scalar guarded path
        int nv = V_LO - v0;
        for (int c = 0; c < C_IN; ++c)
            for (int j = 0; j < nv; ++j) {
                float xs = xb[(size_t)c * V_LO + v0 + j];
#pragma unroll
                for (int o = 0; o < C_OUT; ++o)
                    acc[o][j] += xs * sW[o * C_IN + c];
            }
        ushort* hp = h + (size_t)b * C_OUT * V_LO + v0;
#pragma unroll
        for (int o = 0; o < C_OUT; ++o)
            for (int j = 0; j < nv; ++j) {
                __hip_bfloat16 bf = __float2bfloat16(acc[o][j] + sB[o]);
                hp[(size_t)o * V_LO + j] = *(ushort*)&bf;
            }
    }
}

// ---------------------------------------------------------------------------
// Inverse-map build: for each u in [0,V_HI), list of (v,k) with
// up_neigh[down[v],k] == u.  Entries packed as (v<<3)|k.
// ---------------------------------------------------------------------------
__global__ __launch_bounds__(256) void count_k(
    const int* __restrict__ up, const int* __restrict__ down,
    unsigned* __restrict__ cnt)
{
    int v = blockIdx.x * 256 + threadIdx.x;
    if (v >= V_LO) return;
    int d = down[v];
    const int* row = up + (size_t)d * K_;
    for (int k = 0; k < K_; ++k)
        atomicAdd(&cnt[row[k]], 1u);
}

__global__ __launch_bounds__(256) void blocksum_k(
    const unsigned* __restrict__ cnt, unsigned* __restrict__ partials)
{
    __shared__ unsigned s[256];
    int i = blockIdx.x * 256 + threadIdx.x;
    unsigned v = (i < V_HI) ? cnt[i] : 0u;
    s[threadIdx.x] = v;
    __syncthreads();
    for (int off = 128; off > 0; off >>= 1) {
        if (threadIdx.x < off) s[threadIdx.x] += s[threadIdx.x + off];
        __syncthreads();
    }
    if (threadIdx.x == 0) partials[blockIdx.x] = s[0];
}

__global__ __launch_bounds__(1024) void scanpart_k(unsigned* __restrict__ partials)
{
    __shared__ unsigned s[1024];
    int t = threadIdx.x;
    unsigned v = (t < NPART) ? partials[t] : 0u;
    s[t] = v;
    __syncthreads();
    for (int off = 1; off < 1024; off <<= 1) {
        unsigned add = (t >= off) ? s[t - off] : 0u;
        __syncthreads();
        s[t] += add;
        __syncthreads();
    }
    if (t < NPART) partials[t] = s[t] - v;   // exclusive
}

__global__ __launch_bounds__(256) void addoff_k(
    const unsigned* __restrict__ cnt, const unsigned* __restrict__ partials,
    unsigned* __restrict__ offsets, unsigned* __restrict__ cursor)
{
    __shared__ unsigned s[256];
    int t = threadIdx.x;
    int i = blockIdx.x * 256 + t;
    unsigned c = (i < V_HI) ? cnt[i] : 0u;
    s[t] = c;
    __syncthreads();
    for (int off = 1; off < 256; off <<= 1) {
        unsigned add = (t >= off) ? s[t - off] : 0u;
        __syncthreads();
        s[t] += add;
        __syncthreads();
    }
    unsigned excl = s[t] - c + partials[blockIdx.x];
    if (i < V_HI) { offsets[i] = excl; cursor[i] = excl; }
    if (i == 0) offsets[V_HI] = (unsigned)TOTAL_E;
}

__global__ __launch_bounds__(256) void scatter_k(
    const int* __restrict__ up, const int* __restrict__ down,
    unsigned* __restrict__ cursor, unsigned* __restrict__ entries)
{
    int v = blockIdx.x * 256 + threadIdx.x;
    if (v >= V_LO) return;
    int d = down[v];
    const int* row = up + (size_t)d * K_;
    for (int k = 0; k < K_; ++k) {
        int u = row[k];
        unsigned pos = atomicAdd(&cursor[u], 1u);
        entries[pos] = ((unsigned)v << 3) | (unsigned)k;
    }
}

// ---------------------------------------------------------------------------
// Count-sorted tile permutation (pair-independent, built once per call):
// within each 1024-u tile, order u's by bucket count so each wave's 64 u's
// have near-equal candidate counts (kills inner-loop divergence in gather).
// Any permutation is correct; winner-per-u is order-independent.
// ---------------------------------------------------------------------------
__global__ __launch_bounds__(1024) void permtile_k(
    const unsigned* __restrict__ cnt, ushort* __restrict__ perm)
{
    __shared__ unsigned hist[16];
    __shared__ unsigned base[16];
    int t = threadIdx.x;
    int u = blockIdx.x * 1024 + t;
    if (t < 16) hist[t] = 0;
    __syncthreads();
    bool valid = (u < V_HI);
    unsigned c = 0, rank = 0;
    if (valid) {
        c = cnt[u];
        if (c > 15u) c = 15u;
        rank = atomicAdd(&hist[c], 1u);
    }
    __syncthreads();
    if (t == 0) {
        unsigned r = 0;
        for (int i = 0; i < 16; ++i) { base[i] = r; r += hist[i]; }
    }
    __syncthreads();
    if (valid) perm[blockIdx.x * 1024 + base[c] + rank] = (ushort)t;
}

// ---------------------------------------------------------------------------
// Pass 3: one block per (b,o) pair. mp slice staged as bytes in LDS (41 KB ->
// 2 blocks/CU, 100% wave occupancy). u's visited in count-sorted tile order.
// Winner h read from global (L2/L3-resident bf16 slice), ~0.25 reads per u.
// ---------------------------------------------------------------------------
__global__ __launch_bounds__(1024) void gather_out_k(
    const unsigned* __restrict__ offsets, const unsigned* __restrict__ entries,
    const int* __restrict__ mp, const ushort* __restrict__ h,
    const ushort* __restrict__ perm, float* __restrict__ out)
{
    __shared__ unsigned char s_mp[V_LO + 2];

    int pair = blockIdx.x;                       // b*C_OUT + o
    const int*    mpp = mp  + (size_t)pair * V_LO;
    const ushort* hp  = h   + (size_t)pair * V_LO;
    float*        op  = out + (size_t)pair * V_HI;

    for (int i = threadIdx.x; i < V_LO; i += 1024)
        s_mp[i] = (unsigned char)mpp[i];         // coalesced global read
    __syncthreads();

    for (int tb = 0; tb < V_HI; tb += 1024) {
        int slot = tb + threadIdx.x;
        if (slot < V_HI) {
            int pu = tb + (int)perm[slot];       // count-sorted u within tile
            unsigned s0 = offsets[pu];
            unsigned s1 = offsets[pu + 1];
            int best = -1;
            for (unsigned e = s0; e < s1; ++e) {
                unsigned p = entries[e];
                int v = (int)(p >> 3);
                if (s_mp[v] == (p & 7u) && v > best) best = v;
            }
            float r = 0.0f;
            if (best >= 0)
                r = __uint_as_float(((unsigned)hp[best]) << 16);  // bf16->f32
            op[pu] = r;   // scattered only within the tile's 4 KB window
        }
    }
}

// ---------------------------------------------------------------------------
extern "C" void kernel_launch(void* const* d_in, const int* in_sizes, int n_in,
                              void* d_out, int out_size, void* d_ws, size_t ws_size,
                              hipStream_t stream)
{
    const float* x    = (const float*)d_in[0];
    const float* W    = (const float*)d_in[1];
    const float* bias = (const float*)d_in[2];
    const int*   mp   = (const int*)d_in[3];
    const int*   up   = (const int*)d_in[4];
    const int*   down = (const int*)d_in[5];
    float* out = (float*)d_out;

    // Workspace layout (bytes)
    char* ws = (char*)d_ws;
    const size_t H_BYTES   = (size_t)B_ * C_OUT * V_LO * 2;       // bf16 h
    const size_t CNT_OFF   = H_BYTES;
    const size_t OFF_OFF   = CNT_OFF + (size_t)V_HI * 4;
    const size_t CUR_OFF   = OFF_OFF + (size_t)(V_HI + 1) * 4;
    const size_t ENT_OFF   = CUR_OFF + (size_t)V_HI * 4;
    const size_t PART_OFF  = ENT_OFF + (size_t)TOTAL_E * 4;
    const size_t PERM_OFF  = PART_OFF + (size_t)NPART * 4 + 64;

    ushort*   h       = (ushort*)ws;
    unsigned* cnt     = (unsigned*)(ws + CNT_OFF);
    unsigned* offsets = (unsigned*)(ws + OFF_OFF);
    unsigned* cursor  = (unsigned*)(ws + CUR_OFF);
    unsigned* entries = (unsigned*)(ws + ENT_OFF);
    unsigned* partials= (unsigned*)(ws + PART_OFF);
    ushort*   perm    = (ushort*)(ws + PERM_OFF);

    // zero the count array (workspace is poisoned 0xAA every call)
    hipMemsetAsync(cnt, 0, (size_t)V_HI * 4, stream);

    // Pass 1: h (4 v per thread)
    {
        dim3 grid((V_LO + 1023) / 1024, B_);     // 41 x 16
        compute_h_k<<<grid, 256, 0, stream>>>(x, W, bias, h);
    }

    // Inverse map build + tile permutation
    {
        int vblk = (V_LO + 255) / 256;           // 161
        count_k<<<vblk, 256, 0, stream>>>(up, down, cnt);
        blocksum_k<<<NPART, 256, 0, stream>>>(cnt, partials);
        scanpart_k<<<1, 1024, 0, stream>>>(partials);
        addoff_k<<<NPART, 256, 0, stream>>>(cnt, partials, offsets, cursor);
        scatter_k<<<vblk, 256, 0, stream>>>(up, down, cursor, entries);
        permtile_k<<<NTILE, 1024, 0, stream>>>(cnt, perm);
    }

    // Pass 3: output
    gather_out_k<<<B_ * C_OUT, 1024, 0, stream>>>(offsets, entries, mp, h, perm, out);
}